// Round 2
// baseline (142.351 us; speedup 1.0000x reference)
//
#include <hip/hip_runtime.h>
#include <math.h>

// B=16384 rows, C=1000 cols, fp32 -> 16384 fp32. Memory-bound: 131 MB total,
// floor ~21 us at 6.3 TB/s.
//
// R2 design: one wave per row, TWO rows per wave (grid-stride by 8192), with
// row-1's 16 float4 loads issued before row-0's reduce so 8 KB stays in
// flight during the dependent shuffle chain. Top-2 is index-free/branchless:
// loo(j) = (v==m1) ? m2 : m1 (tie-safe: duplicated max => m2==m1).

constexpr int kC  = 1000;
constexpr int kNV = kC / 4;        // 250 float4 per row
constexpr int kRowsPerWavePass = 2;

__device__ __forceinline__ void load_row(const float* __restrict__ y1,
                                         const float* __restrict__ y2,
                                         int row, int lane,
                                         float4* A, float4* B, int nrows)
{
    const float4 ninf4 = make_float4(-INFINITY, -INFINITY, -INFINITY, -INFINITY);
    if (row < nrows) {
        const float4* r1 = reinterpret_cast<const float4*>(y1) + (size_t)row * kNV;
        const float4* r2 = reinterpret_cast<const float4*>(y2) + (size_t)row * kNV;
#pragma unroll
        for (int c = 0; c < 4; ++c) {
            const int vi = lane + 64 * c;
            if (vi < kNV) { A[c] = r1[vi]; B[c] = r2[vi]; }
            else          { A[c] = ninf4;  B[c] = ninf4; }
        }
    } else {
#pragma unroll
        for (int c = 0; c < 4; ++c) { A[c] = ninf4; B[c] = ninf4; }
    }
}

__device__ __forceinline__ float process_row(const float4* A, const float4* B)
{
    // pass 1: per-lane branchless top-2 for both inputs
    float m1 = -INFINITY, m2 = -INFINITY;
    float n1 = -INFINITY, n2 = -INFINITY;
#pragma unroll
    for (int c = 0; c < 4; ++c) {
        const float* av = reinterpret_cast<const float*>(&A[c]);
        const float* bv = reinterpret_cast<const float*>(&B[c]);
#pragma unroll
        for (int k = 0; k < 4; ++k) {
            const float v = av[k];
            m2 = fmaxf(m2, fminf(m1, v)); m1 = fmaxf(m1, v);
            const float w = bv[k];
            n2 = fmaxf(n2, fminf(n1, w)); n1 = fmaxf(n1, w);
        }
    }
    // wave butterfly: merge (top1, top2) pairs; all lanes converge
#pragma unroll
    for (int off = 32; off > 0; off >>= 1) {
        const float o1 = __shfl_xor(m1, off, 64);
        const float o2 = __shfl_xor(m2, off, 64);
        m2 = fmaxf(fminf(m1, o1), fmaxf(m2, o2));
        m1 = fmaxf(m1, o1);
        const float p1 = __shfl_xor(n1, off, 64);
        const float p2 = __shfl_xor(n2, off, 64);
        n2 = fmaxf(fminf(n1, p1), fmaxf(n2, p2));
        n1 = fmaxf(n1, p1);
    }
    // pass 2: max_j min(v - loo1, w - loo2), register-resident
    float best = -INFINITY;
#pragma unroll
    for (int c = 0; c < 4; ++c) {
        const float* av = reinterpret_cast<const float*>(&A[c]);
        const float* bv = reinterpret_cast<const float*>(&B[c]);
#pragma unroll
        for (int k = 0; k < 4; ++k) {
            const float v = av[k];
            const float w = bv[k];
            const float l1 = (v == m1) ? m2 : m1;
            const float l2 = (w == n1) ? n2 : n1;
            best = fmaxf(best, fminf(v - l1, w - l2));
        }
    }
#pragma unroll
    for (int off = 32; off > 0; off >>= 1)
        best = fmaxf(best, __shfl_xor(best, off, 64));
    return best;
}

__global__ __launch_bounds__(256, 5) void netsat_kernel(
    const float* __restrict__ y1, const float* __restrict__ y2,
    float* __restrict__ out, int nrows)
{
    const int lane = threadIdx.x & 63;
    const int wave = threadIdx.x >> 6;
    const int waves_total = gridDim.x * 4;
    const int w_id = blockIdx.x * 4 + wave;
    const int row0 = w_id;
    const int row1 = w_id + waves_total;

    float4 A0[4], B0[4], A1[4], B1[4];
    load_row(y1, y2, row0, lane, A0, B0, nrows);
    load_row(y1, y2, row1, lane, A1, B1, nrows);  // in flight during row0 reduce

    const float best0 = process_row(A0, B0);
    if (lane == 0 && row0 < nrows) out[row0] = best0;

    const float best1 = process_row(A1, B1);
    if (lane == 0 && row1 < nrows) out[row1] = best1;
}

extern "C" void kernel_launch(void* const* d_in, const int* in_sizes, int n_in,
                              void* d_out, int out_size, void* d_ws, size_t ws_size,
                              hipStream_t stream) {
    const float* y1 = (const float*)d_in[0];
    const float* y2 = (const float*)d_in[1];
    float* out = (float*)d_out;
    const int nrows = out_size;  // 16384
    const int waves_needed = (nrows + kRowsPerWavePass - 1) / kRowsPerWavePass;  // 8192
    const int blocks = (waves_needed + 3) / 4;  // 2048
    netsat_kernel<<<blocks, 256, 0, stream>>>(y1, y2, out, nrows);
}

// Round 3
// 139.800 us; speedup vs baseline: 1.0182x; 1.0182x over previous
//
#include <hip/hip_runtime.h>
#include <math.h>

// B=16384 rows, C=1000 cols, fp32 -> 16384 fp32. Memory-bound: 131 MB, floor
// ~21 us at 6.3 TB/s.
//
// R3: one wave per row, payload GENUINELY register-resident.
// __launch_bounds__(256,4) grants 128 VGPRs/wave so the 16 float4 (64 VGPR)
// payload stays live across pass 1 and pass 2 — R1/R2 compiled to 36/44 VGPRs,
// proving the compiler was re-loading from global in pass 2 and serializing
// loads in small batches (exposed latency). Loads are unconditional (tail
// chunk index-clamped, masked to -inf after load) so all 16 hoist cleanly.

constexpr int kC  = 1000;
constexpr int kNV = kC / 4;        // 250 float4 per row
constexpr int kRowsPerBlock = 4;

__global__ __launch_bounds__(256, 4) void netsat_kernel(
    const float* __restrict__ y1, const float* __restrict__ y2,
    float* __restrict__ out, int nrows)
{
    const int lane = threadIdx.x & 63;
    const int wave = threadIdx.x >> 6;
    const int row  = blockIdx.x * kRowsPerBlock + wave;
    if (row >= nrows) return;

    const float4* r1 = reinterpret_cast<const float4*>(y1) + (size_t)row * kNV;
    const float4* r2 = reinterpret_cast<const float4*>(y2) + (size_t)row * kNV;

    // All 16 loads unconditional and hoisted; 8 KB/wave in flight.
    const int vi3 = (lane + 192 < kNV) ? (lane + 192) : (kNV - 1);  // clamp
    float4 A[4], B[4];
    A[0] = r1[lane];       B[0] = r2[lane];
    A[1] = r1[lane + 64];  B[1] = r2[lane + 64];
    A[2] = r1[lane + 128]; B[2] = r2[lane + 128];
    A[3] = r1[vi3];        B[3] = r2[vi3];

    const bool tail_ok = (lane + 192) < kNV;
    const float4 ninf4 = make_float4(-INFINITY, -INFINITY, -INFINITY, -INFINITY);
    if (!tail_ok) { A[3] = ninf4; B[3] = ninf4; }   // cndmask, post-load

    // ---- pass 1: per-lane branchless top-2 for both inputs ----
    float m1 = -INFINITY, m2 = -INFINITY;
    float n1 = -INFINITY, n2 = -INFINITY;
#pragma unroll
    for (int c = 0; c < 4; ++c) {
        const float* av = reinterpret_cast<const float*>(&A[c]);
        const float* bv = reinterpret_cast<const float*>(&B[c]);
#pragma unroll
        for (int k = 0; k < 4; ++k) {
            const float v = av[k];
            m2 = fmaxf(m2, fminf(m1, v)); m1 = fmaxf(m1, v);
            const float w = bv[k];
            n2 = fmaxf(n2, fminf(n1, w)); n1 = fmaxf(n1, w);
        }
    }

    // ---- wave butterfly: merge (top1, top2); m/n chains interleave (ILP) ----
#pragma unroll
    for (int off = 32; off > 0; off >>= 1) {
        const float o1 = __shfl_xor(m1, off, 64);
        const float o2 = __shfl_xor(m2, off, 64);
        const float p1 = __shfl_xor(n1, off, 64);
        const float p2 = __shfl_xor(n2, off, 64);
        m2 = fmaxf(fminf(m1, o1), fmaxf(m2, o2));
        m1 = fmaxf(m1, o1);
        n2 = fmaxf(fminf(n1, p1), fmaxf(n2, p2));
        n1 = fmaxf(n1, p1);
    }

    // ---- pass 2: max_j min(v - loo1, w - loo2) over REGISTER values ----
    // loo(v) = (v==m1) ? m2 : m1 — tie-safe (duplicated max => m2==m1).
    float best = -INFINITY;
#pragma unroll
    for (int c = 0; c < 4; ++c) {
        const float* av = reinterpret_cast<const float*>(&A[c]);
        const float* bv = reinterpret_cast<const float*>(&B[c]);
#pragma unroll
        for (int k = 0; k < 4; ++k) {
            const float v = av[k];
            const float w = bv[k];
            const float l1 = (v == m1) ? m2 : m1;
            const float l2 = (w == n1) ? n2 : n1;
            best = fmaxf(best, fminf(v - l1, w - l2));
        }
    }
#pragma unroll
    for (int off = 32; off > 0; off >>= 1)
        best = fmaxf(best, __shfl_xor(best, off, 64));

    if (lane == 0) out[row] = best;
}

extern "C" void kernel_launch(void* const* d_in, const int* in_sizes, int n_in,
                              void* d_out, int out_size, void* d_ws, size_t ws_size,
                              hipStream_t stream) {
    const float* y1 = (const float*)d_in[0];
    const float* y2 = (const float*)d_in[1];
    float* out = (float*)d_out;
    const int nrows = out_size;  // 16384
    const int blocks = (nrows + kRowsPerBlock - 1) / kRowsPerBlock;  // 4096
    netsat_kernel<<<blocks, 256, 0, stream>>>(y1, y2, out, nrows);
}